// Round 3
// baseline (135.593 us; speedup 1.0000x reference)
//
#include <hip/hip_runtime.h>

// Problem constants
#define NN 16        // batch
#define PB 16        // predicted masks
#define TB 8         // true masks
#define HWPX 50176   // 224*224
#define WORDS 784    // u64 words per plane (50176/64)
#define HALF 392     // words per half-plane
#define GROUPS 196   // 256-pixel groups per plane
#define TOTAL_GROUPS ((NN * PB + NN * TB) * GROUPS)  // 75264
#define K3_CH 16     // score-phase blocks per batch element
#define WPC (WORDS / K3_CH)  // 49 words per score chunk

// ---------------------------------------------------------------------------
// K1: bitpack both inputs (77 MB fp32 -> 2.4 MB bits) + zero d_out.
// Each wave-iteration: 64 lanes load float4 (1 KiB coalesced), 4 ballots
// produce 4 u64 words, lane 0 stores 32 B. Pixel->bit mapping is a fixed
// permutation identical for pred and true planes, so popcount intersections
// and the permutation-invariant final mean are unaffected.
// HBM-bound: 77 MB compulsory read ~= 12 us at 6.4 TB/s.
// ---------------------------------------------------------------------------
__global__ __launch_bounds__(256) void pack_kernel(
        const float* __restrict__ pred, const float* __restrict__ truth,
        unsigned long long* __restrict__ PP, unsigned long long* __restrict__ PT,
        float* __restrict__ out) {
    if (blockIdx.x == 0 && threadIdx.x < NN) out[threadIdx.x] = 0.f;

    const int wavesPerBlock = blockDim.x >> 6;
    const int waveId = blockIdx.x * wavesPerBlock + (threadIdx.x >> 6);
    const int lane = threadIdx.x & 63;
    const int nWaves = gridDim.x * wavesPerBlock;

    for (int G = waveId; G < TOTAL_GROUPS; G += nWaves) {
        int plane = G / GROUPS;
        int g = G - plane * GROUPS;
        const float* src;
        unsigned long long* dst;
        if (plane < NN * PB) {
            src = pred + (size_t)plane * HWPX;
            dst = PP + (size_t)plane * WORDS;
        } else {
            int q = plane - NN * PB;
            src = truth + (size_t)q * HWPX;
            dst = PT + (size_t)q * WORDS;
        }
        const float4 v = *(const float4*)(src + g * 256 + lane * 4);
        unsigned long long b0 = __ballot(v.x != 0.0f);
        unsigned long long b1 = __ballot(v.y != 0.0f);
        unsigned long long b2 = __ballot(v.z != 0.0f);
        unsigned long long b3 = __ballot(v.w != 0.0f);
        if (lane == 0) {
            ulonglong2 lo, hi;
            lo.x = b0; lo.y = b1; hi.x = b2; hi.y = b3;
            ((ulonglong2*)dst)[g * 2 + 0] = lo;
            ((ulonglong2*)dst)[g * 2 + 1] = hi;
        }
    }
}

// ---------------------------------------------------------------------------
// K2: iou_maxs[n,:] computed ONCE per n (round-2 lesson: replicating this
// x16 per n cost +10 us of L2 traffic). 16 blocks, 256 threads; each (p,t)
// pair is handled by 2 threads (one half-plane each), combined via shfl_xor.
// Reads 1.6 MB/block from L2; writes 16 floats.
// ---------------------------------------------------------------------------
__global__ __launch_bounds__(256) void ioumax_kernel(
        const unsigned long long* __restrict__ PP,
        const unsigned long long* __restrict__ PT,
        float* __restrict__ ioumax) {
    const int n = blockIdx.x;
    const int tid = threadIdx.x;

    __shared__ int inters_s[PB * TB];
    __shared__ int sp_s[PB];
    __shared__ int st_s[TB];

    const int pair = tid >> 1;       // 0..127 -> (p,t)
    const int h = tid & 1;           // which half of the plane
    const int p = pair >> 3, t = pair & 7;
    const ulonglong2* pp2 =
        (const ulonglong2*)(PP + ((size_t)n * PB + p) * WORDS + h * HALF);
    const ulonglong2* pt2 =
        (const ulonglong2*)(PT + ((size_t)n * TB + t) * WORDS + h * HALF);
    int acc = 0, accp = 0, acct = 0;
#pragma unroll 4
    for (int i = 0; i < HALF / 2; ++i) {
        ulonglong2 a = pp2[i];
        ulonglong2 b = pt2[i];
        acc  += __popcll(a.x & b.x) + __popcll(a.y & b.y);
        accp += __popcll(a.x) + __popcll(a.y);
        acct += __popcll(b.x) + __popcll(b.y);
    }
    acc  += __shfl_xor(acc, 1, 64);   // combine the two half-planes
    accp += __shfl_xor(accp, 1, 64);
    acct += __shfl_xor(acct, 1, 64);
    if (h == 0) {
        inters_s[pair] = acc;
        if (t == 0) sp_s[p] = accp;
        if (p == 0) st_s[t] = acct;
    }
    __syncthreads();

    if (tid < PB) {
        float spv = (float)sp_s[tid];
        float m = 0.f;
#pragma unroll
        for (int tt = 0; tt < TB; ++tt) {
            float iv = (float)inters_s[tid * TB + tt];
            float un = spv + (float)st_s[tt] - iv;
            m = fmaxf(m, un > 0.f ? iv / un : 0.f);
        }
        ioumax[n * PB + tid] = m;
    }
}

// ---------------------------------------------------------------------------
// K3: score. 256 blocks (16 chunks per n), 256 threads. Division-free: the
// per-pixel denominator is an integer in [0,16] -> 17-entry LDS reciprocal
// table (entry 0 = 0 implements the isfinite->0 rule). Word loads are
// wave-uniform (one L2 line per wave), lanes extract their pixel bit.
// ---------------------------------------------------------------------------
__global__ __launch_bounds__(256) void score_kernel(
        const unsigned long long* __restrict__ PP,
        const float* __restrict__ ioumax,
        float* __restrict__ out) {
    const int n = blockIdx.x / K3_CH;
    const int c = blockIdx.x % K3_CH;
    const int tid = threadIdx.x;

    __shared__ float rcp_s[17];
    __shared__ float red_s[4];
    if (tid < 17) rcp_s[tid] = tid ? 1.0f / (float)tid : 0.0f;

    float iom[PB];
#pragma unroll
    for (int q = 0; q < PB; ++q) iom[q] = ioumax[n * PB + q];
    __syncthreads();

    const int lane = tid & 63;
    const int wv = tid >> 6;
    const unsigned long long* base = PP + (size_t)n * PB * WORDS;
    float sum = 0.f;
    for (int w = c * WPC + wv; w < (c + 1) * WPC; w += 4) {
        float num = 0.f;
        unsigned int den = 0;
#pragma unroll
        for (int q = 0; q < PB; ++q) {
            unsigned long long m = base[(size_t)q * WORDS + w];
            unsigned int bit = (unsigned int)(m >> lane) & 1u;
            den += bit;
            num = fmaf((float)bit, iom[q], num);
        }
        sum += num * rcp_s[den];
    }

#pragma unroll
    for (int off = 32; off > 0; off >>= 1) sum += __shfl_down(sum, off, 64);
    if (lane == 0) red_s[wv] = sum;
    __syncthreads();
    if (tid == 0) {
        atomicAdd(&out[n],
                  (red_s[0] + red_s[1] + red_s[2] + red_s[3]) * (1.0f / (float)HWPX));
    }
}

// ---------------------------------------------------------------------------
extern "C" void kernel_launch(void* const* d_in, const int* in_sizes, int n_in,
                              void* d_out, int out_size, void* d_ws, size_t ws_size,
                              hipStream_t stream) {
    const float* pred  = (const float*)d_in[0];   // (N,P,H,W) fp32 {0,1}
    const float* truth = (const float*)d_in[1];   // (N,T,H,W) fp32 {0,1}
    float* out = (float*)d_out;                   // (N,)

    unsigned long long* PP = (unsigned long long*)d_ws;      // 200704 u64
    unsigned long long* PT = PP + (size_t)NN * PB * WORDS;   // 100352 u64
    float* ioumax = (float*)(PT + (size_t)NN * TB * WORDS);  // 256 f32

    pack_kernel<<<2048, 256, 0, stream>>>(pred, truth, PP, PT, out);
    ioumax_kernel<<<NN, 256, 0, stream>>>(PP, PT, ioumax);
    score_kernel<<<NN * K3_CH, 256, 0, stream>>>(PP, ioumax, out);
}